// Round 3
// baseline (4830.499 us; speedup 1.0000x reference)
//
#include <hip/hip_runtime.h>
#include <hip/hip_bf16.h>
#include <hip/hip_fp16.h>

// SARDecoder: 31-step teacher-forced attention LSTM decoder.
// fp32 in/out (per reference dtypes), fp32 compute, bf16/fp16 internal buffers.
// B=32, RNN=ATT=FEAT=512, V1=111, H=8, W=32, STEPS=31, P=H*W=256.

#define RNN   512
#define V1    111
#define STEPS 31
#define HWP   256
#define G4    2048   // 4*RNN
#define KC    16     // split-K chunks per gate GEMM (64 k each)

typedef unsigned short ushortT;
typedef unsigned int   uintT;

__device__ __forceinline__ float b2f(ushortT s){
  union { uintT i; float f; } v; v.i = ((uintT)s) << 16; return v.f;
}
__device__ __forceinline__ float blo(uintT u){ union { uintT i; float f; } v; v.i = u << 16; return v.f; }
__device__ __forceinline__ float bhi(uintT u){ union { uintT i; float f; } v; v.i = u & 0xffff0000u; return v.f; }
__device__ __forceinline__ ushortT f2b(float f){
  __hip_bfloat16 h = __float2bfloat16(f);
  union { __hip_bfloat16 b; ushortT s; } v; v.b = h; return v.s;
}
__device__ __forceinline__ ushortT f2h(float f){
  __half h = __float2half(f);
  union { __half h; ushortT s; } v; v.h = h; return v.s;
}
__device__ __forceinline__ float h2f(ushortT s){
  union { __half h; ushortT s; } v; v.s = s; return __half2float(v.h);
}
__device__ __forceinline__ float sigf(float x){ return 1.f/(1.f + __expf(-x)); }
__device__ __forceinline__ float tanh_f(float x){ float e = __expf(2.f*x); return 1.f - 2.f/(e+1.f); }

// ---------------- init: zero the 4 LSTM state arrays (65536 floats) ----------------
__global__ __launch_bounds__(256) void k_init(float* __restrict__ p){
  p[blockIdx.x*256 + threadIdx.x] = 0.f;
}

// ---------------- conv 3x3 SAME -> fpj bf16, layout (b, p, a), p = y*32+x ----------------
// grid 512: bid -> b (32) x y (8) x a-half (2); 256 threads = a within half.
__global__ __launch_bounds__(256) void k_conv(const float* __restrict__ feat,
                                              const float* __restrict__ Wf,
                                              const float* __restrict__ bfv,
                                              ushortT* __restrict__ fpj){
  int bid = blockIdx.x;
  int b  = bid >> 4;
  int y  = (bid >> 1) & 7;
  int ah = bid & 1;
  int a  = ah*256 + threadIdx.x;
  float acc[32];
  float bias = bfv[a];
  #pragma unroll
  for (int x=0;x<32;x++) acc[x]=bias;
  for (int c=0;c<512;c++){
    const float* wrow = Wf + ((size_t)a*512 + (size_t)c)*9;
    float w[9];
    #pragma unroll
    for (int i=0;i<9;i++) w[i] = wrow[i];   // 9-float rows: scalar loads (36B, unaligned for float4)
    #pragma unroll
    for (int ky=0;ky<3;ky++){
      int yy = y + ky - 1;
      if (yy < 0 || yy > 7) continue;            // y uniform per block -> no divergence
      const float4* irow = (const float4*)(feat + (((size_t)b*512 + c)*8 + yy)*32);
      float in[32];
      #pragma unroll
      for (int i=0;i<8;i++){
        float4 q = irow[i];
        in[4*i]=q.x; in[4*i+1]=q.y; in[4*i+2]=q.z; in[4*i+3]=q.w;
      }
      float w0=w[ky*3+0], w1=w[ky*3+1], w2=w[ky*3+2];
      #pragma unroll
      for (int x=0;x<32;x++){
        float s = w1*in[x];
        if (x>0)  s += w0*in[x-1];
        if (x<31) s += w2*in[x+1];
        acc[x] += s;
      }
    }
  }
  // store (b, p, a) bf16: for fixed x, a is consecutive across threads -> coalesced 2B stores
  #pragma unroll
  for (int x=0;x<32;x++)
    fpj[((size_t)b*HWP + (size_t)(y*32+x))*512 + a] = f2b(acc[x]);
}

// ---------------- split-K gate GEMM core ----------------
// Computes partial gates[b][j] over this block's 64-wide k-slice; writes fp16 gp[kc][b][j].
__device__ __forceinline__ void gemm_core(const float* __restrict__ wrow,
                                          ushortT* __restrict__ gp,
                                          const float* xh_s, int kc, int j){
  float acc[32];
  #pragma unroll
  for (int b=0;b<32;b++) acc[b]=0.f;
  #pragma unroll
  for (int kb=0;kb<8;kb++){
    float4 wa = *(const float4*)(wrow + kb*8);
    float4 wb = *(const float4*)(wrow + kb*8 + 4);
    #pragma unroll
    for (int b=0;b<32;b++){
      const float* xr = xh_s + b*64 + kb*8;
      float4 xa = *(const float4*)xr;
      float4 xb = *(const float4*)(xr+4);
      acc[b] += wa.x*xa.x + wa.y*xa.y + wa.z*xa.z + wa.w*xa.w
              + wb.x*xb.x + wb.y*xb.y + wb.z*xb.z + wb.w*xb.w;
    }
  }
  ushortT* op = gp + (size_t)kc*(32*G4) + j;
  #pragma unroll
  for (int b=0;b<32;b++) op[(size_t)b*G4] = f2h(acc[b]);
}

// ---------------- cell-0 gates: x = one-hot embedding gather (or zeros at t=0) ----------------
__global__ __launch_bounds__(512) void k_gates0(int t, const int* __restrict__ gt,
    const float* __restrict__ Wemb,
    const float* __restrict__ wih0, const float* __restrict__ whh0,
    const float* __restrict__ h0, ushortT* __restrict__ gp0){
  __shared__ __align__(16) float xh_s[2048];
  int kc = blockIdx.x & 15, jg = blockIdx.x >> 4, tid = threadIdx.x;
  for (int idx = tid; idx < 2048; idx += 512){
    int b = idx >> 6, kk = idx & 63;
    float v;
    if (kc < 8){
      v = 0.f;
      if (t > 0){
        int g = gt[b*STEPS + t - 1];
        v = Wemb[(size_t)(kc*64 + kk)*V1 + g];
      }
    } else {
      v = h0[b*RNN + (kc-8)*64 + kk];
    }
    xh_s[idx] = v;
  }
  __syncthreads();
  int j = jg*512 + tid;
  const float* wrow = (kc < 8) ? (wih0 + (size_t)j*512 + kc*64)
                               : (whh0 + (size_t)j*512 + (kc-8)*64);
  gemm_core(wrow, gp0, xh_s, kc, j);
}

// ---------------- cell-1 gates: inputs are h0 (new) and h1 (prev) ----------------
__global__ __launch_bounds__(512) void k_gates1(const float* __restrict__ h0,
    const float* __restrict__ h1,
    const float* __restrict__ wih1, const float* __restrict__ whh1,
    ushortT* __restrict__ gp1){
  __shared__ __align__(16) float xh_s[2048];
  int kc = blockIdx.x & 15, jg = blockIdx.x >> 4, tid = threadIdx.x;
  for (int idx = tid; idx < 2048; idx += 512){
    int b = idx >> 6, kk = idx & 63;
    float v = (kc < 8) ? h0[b*RNN + kc*64 + kk]
                       : h1[b*RNN + (kc-8)*64 + kk];
    xh_s[idx] = v;
  }
  __syncthreads();
  int j = jg*512 + tid;
  const float* wrow = (kc < 8) ? (wih1 + (size_t)j*512 + kc*64)
                               : (whh1 + (size_t)j*512 + (kc-8)*64);
  gemm_core(wrow, gp1, xh_s, kc, j);
}

// ---------------- LSTM cell state update: one thread per (b,u), in-place c/h ----------------
__global__ __launch_bounds__(512) void k_cell(const ushortT* __restrict__ gp,
    const float* __restrict__ bih, const float* __restrict__ bhh,
    float* __restrict__ c, float* __restrict__ h){
  int b = blockIdx.x, u = threadIdx.x;
  float gi = bih[u]      + bhh[u];
  float gf = bih[512+u]  + bhh[512+u];
  float gg = bih[1024+u] + bhh[1024+u];
  float go = bih[1536+u] + bhh[1536+u];
  #pragma unroll
  for (int k2=0;k2<KC;k2++){
    const ushortT* base = gp + (size_t)k2*(32*G4) + (size_t)b*G4;
    gi += h2f(base[u]); gf += h2f(base[512+u]);
    gg += h2f(base[1024+u]); go += h2f(base[1536+u]);
  }
  float ii = sigf(gi), ff = sigf(gf), g = tanh_f(gg), o = sigf(go);
  float cp = c[b*RNN + u];
  float cn = ff*cp + ii*g;
  float hn = o * tanh_f(cn);
  c[b*RNN + u] = cn;
  h[b*RNN + u] = hn;
}

// ---------------- attention + output logits; one block per batch item ----------------
__global__ __launch_bounds__(512) void k_att(int t,
    const float* __restrict__ feat,     // (b, c, p) fp32
    const ushortT* __restrict__ fpj,    // (b, p, a) bf16
    const float* __restrict__ h1,
    const float* __restrict__ Wst, const float* __restrict__ watt,
    const float* __restrict__ Wout, const float* __restrict__ bout,
    float* __restrict__ out)
{
  __shared__ __align__(16) float h1s[512];
  __shared__ __align__(16) float sps[512];
  __shared__ __align__(16) float watts[512];
  __shared__ __align__(16) float pals[512];
  __shared__ __align__(16) float attw[256];
  __shared__ __align__(16) float glim[512];
  __shared__ float red[4];
  const int b = blockIdx.x, tid = threadIdx.x;

  h1s[tid]   = h1[b*RNN + tid];
  watts[tid] = watt[tid];
  __syncthreads();

  // sp = h1 @ W_state^T   (one thread per attention unit)
  {
    const float4* wr = (const float4*)(Wst + (size_t)tid*512);
    float acc = 0.f;
    #pragma unroll 8
    for (int kb=0;kb<128;kb++){
      float4 q = wr[kb];
      const float* hx = h1s + kb*4;
      acc += q.x*hx[0] + q.y*hx[1] + q.z*hx[2] + q.w*hx[3];
    }
    sps[tid] = acc;
  }
  __syncthreads();

  // attention logits: thread (p, a-half) accumulates over 256 a's (contiguous bf16)
  {
    int p = tid & 255, ac = tid >> 8;
    const uint4* fr = (const uint4*)(fpj + ((size_t)b*HWP + p)*512 + ac*256);
    float al = 0.f;
    #pragma unroll 8
    for (int kb=0;kb<32;kb++){
      uint4 q = fr[kb];
      float v[8] = {blo(q.x),bhi(q.x),blo(q.y),bhi(q.y),blo(q.z),bhi(q.z),blo(q.w),bhi(q.w)};
      int a0 = ac*256 + kb*8;
      #pragma unroll
      for (int i=0;i<8;i++)
        al += watts[a0+i] * tanh_f(v[i] + sps[a0+i]);
    }
    pals[tid] = al;
  }
  __syncthreads();

  // softmax over 256 positions
  {
    float al = (tid < 256) ? (pals[tid] + pals[256+tid]) : -1e30f;
    float m = al;
    #pragma unroll
    for (int off=32; off>0; off>>=1) m = fmaxf(m, __shfl_xor(m, off));
    if (tid < 256 && (tid & 63)==0) red[tid>>6] = m;
    __syncthreads();
    m = fmaxf(fmaxf(red[0],red[1]), fmaxf(red[2],red[3]));
    float e = (tid < 256) ? __expf(al - m) : 0.f;
    float s = e;
    #pragma unroll
    for (int off=32; off>0; off>>=1) s += __shfl_xor(s, off);
    __syncthreads();                       // red reads (for m) done before overwrite
    if (tid < 256 && (tid & 63)==0) red[tid>>6] = s;
    __syncthreads();
    if (tid < 256){
      float sa = red[0]+red[1]+red[2]+red[3];
      attw[tid] = e / sa;
    }
  }
  __syncthreads();

  // glimpse[c] = sum_p feat[b,c,p] * attw[p]
  {
    const float4* fr = (const float4*)(feat + ((size_t)b*512 + tid)*HWP);
    float acc = 0.f;
    #pragma unroll 8
    for (int kb=0;kb<64;kb++){
      float4 q = fr[kb];
      const float* aw = attw + kb*4;
      acc += q.x*aw[0] + q.y*aw[1] + q.z*aw[2] + q.w*aw[3];
    }
    glim[tid] = acc;
  }
  __syncthreads();

  // logits = [h1, glimpse] @ W_out^T + b_out
  if (tid < V1){
    const float4* wr = (const float4*)(Wout + (size_t)tid*1024);
    float acc = bout[tid];
    #pragma unroll 8
    for (int kb=0;kb<128;kb++){
      float4 q = wr[kb];
      const float* hx = h1s + kb*4;
      acc += q.x*hx[0] + q.y*hx[1] + q.z*hx[2] + q.w*hx[3];
    }
    #pragma unroll 8
    for (int kb=0;kb<128;kb++){
      float4 q = wr[128+kb];
      const float* gx = glim + kb*4;
      acc += q.x*gx[0] + q.y*gx[1] + q.z*gx[2] + q.w*gx[3];
    }
    out[(size_t)b*STEPS*V1 + (size_t)t*V1 + tid] = acc;
  }
}

extern "C" void kernel_launch(void* const* d_in, const int* in_sizes, int n_in,
                              void* d_out, int out_size, void* d_ws, size_t ws_size,
                              hipStream_t stream)
{
  const float* features = (const float*)d_in[0];
  const int*   gt       = (const int*)d_in[2];
  const float* Wf    = (const float*)d_in[3];
  const float* bfv   = (const float*)d_in[4];
  const float* Wst   = (const float*)d_in[5];
  const float* watt  = (const float*)d_in[6];
  const float* Wemb  = (const float*)d_in[7];
  const float* wih0  = (const float*)d_in[8];
  const float* whh0  = (const float*)d_in[9];
  const float* bih0  = (const float*)d_in[10];
  const float* bhh0  = (const float*)d_in[11];
  const float* wih1  = (const float*)d_in[12];
  const float* whh1  = (const float*)d_in[13];
  const float* bih1  = (const float*)d_in[14];
  const float* bhh1  = (const float*)d_in[15];
  const float* Wout  = (const float*)d_in[16];
  const float* bout  = (const float*)d_in[17];
  float* out = (float*)d_out;

  // ---- workspace layout (bytes): total 12,845,056 (~12.25 MiB) ----
  char* wsb = (char*)d_ws;
  ushortT* fpj = (ushortT*)(wsb + 0);            // bf16 (b,p,a): 4,194,304 el = 8,388,608 B
  ushortT* gp0 = (ushortT*)(wsb + 8388608);      // fp16: 1,048,576 el = 2,097,152 B
  ushortT* gp1 = (ushortT*)(wsb + 10485760);     // fp16: 2,097,152 B
  float*   st  = (float*)  (wsb + 12582912);     // fp32 states: 65,536 floats
  float* h0 = st;
  float* c0 = st + 16384;
  float* h1 = st + 32768;
  float* c1 = st + 49152;

  k_init<<<256, 256, 0, stream>>>(st);                       // zero h0,c0,h1,c1
  k_conv<<<512, 256, 0, stream>>>(features, Wf, bfv, fpj);

  for (int t = 0; t < STEPS; t++){
    k_gates0<<<64, 512, 0, stream>>>(t, gt, Wemb, wih0, whh0, h0, gp0);
    k_cell  <<<32, 512, 0, stream>>>(gp0, bih0, bhh0, c0, h0);
    k_gates1<<<64, 512, 0, stream>>>(h0, h1, wih1, whh1, gp1);
    k_cell  <<<32, 512, 0, stream>>>(gp1, bih1, bhh1, c1, h1);
    k_att   <<<32, 512, 0, stream>>>(t, features, fpj, h1, Wst, watt, Wout, bout, out);
  }
  (void)in_sizes; (void)n_in; (void)out_size; (void)ws_size;
}